// Round 1
// baseline (12386.927 us; speedup 1.0000x reference)
//
#include <hip/hip_runtime.h>

#define USER_NUM 200000
#define ITEM_NUM 100000
#define N_NODES  300000   // USER_NUM + ITEM_NUM
#define EMB      64
#define N_EDGES  4800000
#define N_LAYERS 3

// SpMM scatter: out[src] += val * x[dst], COO edges.
// 16 lanes per edge; each lane handles one float4 (4 consecutive floats) of
// the 64-wide embedding row. Gather is a fully-vectorized 256B row read;
// scatter uses hardware global_atomic_add_f32 (unsafeAtomicAdd — no CAS loop).
__global__ __launch_bounds__(256) void spmm_scatter(
    const int*   __restrict__ esrc,
    const int*   __restrict__ edst,
    const float* __restrict__ eval,
    const float* __restrict__ x,
    float*       __restrict__ y)
{
    long long t = (long long)blockIdx.x * blockDim.x + threadIdx.x;
    int e = (int)(t >> 4);
    if (e >= N_EDGES) return;
    int lane = (int)(t & 15);

    int   d = edst[e];
    int   s = esrc[e];
    float v = eval[e];

    float4 g = ((const float4*)(x + (size_t)d * EMB))[lane];
    float* yo = y + (size_t)s * EMB + (size_t)lane * 4;

    unsafeAtomicAdd(yo + 0, g.x * v);
    unsafeAtomicAdd(yo + 1, g.y * v);
    unsafeAtomicAdd(yo + 2, g.z * v);
    unsafeAtomicAdd(yo + 3, g.w * v);
}

// y += x / N_LAYERS  (vectorized float4)
__global__ __launch_bounds__(256) void axpy_third(
    const float* __restrict__ x,
    float*       __restrict__ y,
    int n4)
{
    int i = blockIdx.x * blockDim.x + threadIdx.x;
    if (i >= n4) return;
    const float a = 1.0f / (float)N_LAYERS;
    float4 v = ((const float4*)x)[i];
    float4 o = ((float4*)y)[i];
    o.x += a * v.x;
    o.y += a * v.y;
    o.z += a * v.z;
    o.w += a * v.w;
    ((float4*)y)[i] = o;
}

extern "C" void kernel_launch(void* const* d_in, const int* in_sizes, int n_in,
                              void* d_out, int out_size, void* d_ws, size_t ws_size,
                              hipStream_t stream)
{
    // setup_inputs() dict order:
    const float* user_emb = (const float*)d_in[0];  // [200000, 64] f32
    const float* item_emb = (const float*)d_in[1];  // [100000, 64] f32
    const float* edge_val = (const float*)d_in[2];  // [4.8M] f32
    const int*   edge_src = (const int*)  d_in[3];  // [4.8M] i32
    const int*   edge_dst = (const int*)  d_in[4];  // [4.8M] i32
    float* out = (float*)d_out;                     // [300000, 64] f32 (= acc/3)

    const size_t node_bytes = (size_t)N_NODES * EMB * sizeof(float);  // 76.8 MB

    // Two ping-pong ego buffers in workspace (needs 153.6 MB of ws).
    float* buf0 = (float*)d_ws;
    float* buf1 = (float*)((char*)d_ws + node_bytes);

    // acc accumulates directly in d_out; zero it (harness poisons with 0xAA).
    hipMemsetAsync(d_out, 0, node_bytes, stream);

    // ego0 = concat(user_emb, item_emb)
    hipMemcpyAsync(buf0, user_emb, (size_t)USER_NUM * EMB * sizeof(float),
                   hipMemcpyDeviceToDevice, stream);
    hipMemcpyAsync(buf0 + (size_t)USER_NUM * EMB, item_emb,
                   (size_t)ITEM_NUM * EMB * sizeof(float),
                   hipMemcpyDeviceToDevice, stream);

    const int spmm_threads = N_EDGES * 16;             // 76.8M threads
    const int spmm_blocks  = spmm_threads / 256;       // 300000 (exact)
    const int n4           = N_NODES * EMB / 4;        // 4.8M float4
    const int axpy_blocks  = (n4 + 255) / 256;

    float* cur = buf0;
    float* nxt = buf1;
    for (int l = 0; l < N_LAYERS; ++l) {
        hipMemsetAsync(nxt, 0, node_bytes, stream);
        spmm_scatter<<<spmm_blocks, 256, 0, stream>>>(edge_src, edge_dst,
                                                      edge_val, cur, nxt);
        axpy_third<<<axpy_blocks, 256, 0, stream>>>(nxt, out, n4);
        float* t = cur; cur = nxt; nxt = t;
    }
}

// Round 2
// 1616.739 us; speedup vs baseline: 7.6617x; 7.6617x over previous
//
#include <hip/hip_runtime.h>

#define USER_NUM 200000
#define ITEM_NUM 100000
#define N_NODES  300000   // USER_NUM + ITEM_NUM
#define EMB      64
#define N_EDGES  4800000
#define N_LAYERS 3

#define SCAN_CHUNK 2048   // elements per scan1 block (256 thr x 8)
#define SCAN_NB    ((N_NODES + SCAN_CHUNK - 1) / SCAN_CHUNK)  // 147

// ---------------- CSR build (runs every call; ~4 passes over edges) --------

__global__ __launch_bounds__(256) void hist_kernel(
    const int* __restrict__ esrc, int* __restrict__ cnt)
{
    int e = blockIdx.x * blockDim.x + threadIdx.x;
    if (e >= N_EDGES) return;
    atomicAdd(&cnt[esrc[e]], 1);
}

// Exclusive scan, stage 1: per-block scan of SCAN_CHUNK elements.
__global__ __launch_bounds__(256) void scan1_kernel(
    const int* __restrict__ cnt, int* __restrict__ rowptr,
    int* __restrict__ blockSums)
{
    __shared__ int lds[256];
    int base = blockIdx.x * SCAN_CHUNK + threadIdx.x * 8;
    int v[8];
    int s = 0;
    #pragma unroll
    for (int i = 0; i < 8; ++i) {
        int idx = base + i;
        v[i] = (idx < N_NODES) ? cnt[idx] : 0;
        s += v[i];
    }
    lds[threadIdx.x] = s;
    __syncthreads();
    // Hillis-Steele inclusive scan over 256 partials
    for (int off = 1; off < 256; off <<= 1) {
        int t = (threadIdx.x >= off) ? lds[threadIdx.x - off] : 0;
        __syncthreads();
        lds[threadIdx.x] += t;
        __syncthreads();
    }
    int excl = (threadIdx.x == 0) ? 0 : lds[threadIdx.x - 1];
    if (threadIdx.x == 255) blockSums[blockIdx.x] = lds[255];
    int run = excl;
    #pragma unroll
    for (int i = 0; i < 8; ++i) {
        int idx = base + i;
        if (idx < N_NODES) rowptr[idx] = run;
        run += v[i];
    }
}

// Stage 2: exclusive-scan the (147) block sums in-place, single block.
__global__ __launch_bounds__(256) void scan2_kernel(int* __restrict__ blockSums, int nb)
{
    __shared__ int lds[256];
    int v = (threadIdx.x < nb) ? blockSums[threadIdx.x] : 0;
    lds[threadIdx.x] = v;
    __syncthreads();
    for (int off = 1; off < 256; off <<= 1) {
        int t = (threadIdx.x >= off) ? lds[threadIdx.x - off] : 0;
        __syncthreads();
        lds[threadIdx.x] += t;
        __syncthreads();
    }
    int excl = (threadIdx.x == 0) ? 0 : lds[threadIdx.x - 1];
    if (threadIdx.x < nb) blockSums[threadIdx.x] = excl;
}

// Stage 3: add block offsets; also init the scatter cursors.
__global__ __launch_bounds__(256) void scan3_kernel(
    int* __restrict__ rowptr, int* __restrict__ cursor,
    const int* __restrict__ blockSums)
{
    int idx = blockIdx.x * blockDim.x + threadIdx.x;
    if (idx >= N_NODES) return;
    int r = rowptr[idx] + blockSums[idx / SCAN_CHUNK];
    rowptr[idx] = r;
    cursor[idx] = r;
}

// Permute edges into CSR order: edges_s[p] = (dst, val) packed 8B.
__global__ __launch_bounds__(256) void scatter_kernel(
    const int* __restrict__ esrc, const int* __restrict__ edst,
    const float* __restrict__ eval, int* __restrict__ cursor,
    int2* __restrict__ edges_s)
{
    int e = blockIdx.x * blockDim.x + threadIdx.x;
    if (e >= N_EDGES) return;
    int s = esrc[e];
    int p = atomicAdd(&cursor[s], 1);
    edges_s[p] = make_int2(edst[e], __float_as_int(eval[e]));
}

// ---------------- CSR SpMM: one wave per row, lane = column -----------------
// y[row][lane] = sum_e val_e * x[dst_e][lane];  acc += y/3 fused.
// Input x is given as two base pointers (user rows, item rows) so layer 0 can
// read the un-concatenated inputs; for ws buffers pass itemp = userp+USER*64.
__global__ __launch_bounds__(256) void spmm_csr(
    const int2*  __restrict__ edges_s,
    const int*   __restrict__ rowptr,
    const int*   __restrict__ cnt,
    const float* __restrict__ userp,
    const float* __restrict__ itemp,
    float*       __restrict__ y,
    float*       __restrict__ acc,
    int layer)
{
    int wid  = (blockIdx.x * blockDim.x + threadIdx.x) >> 6;   // row
    int lane = threadIdx.x & 63;                                // column
    if (wid >= N_NODES) return;

    int start = rowptr[wid];
    int deg   = cnt[wid];

    float a = 0.0f;
    for (int base = 0; base < deg; base += 64) {
        int m = deg - base;
        if (m > 64) m = 64;
        int2 e = make_int2(0, 0);
        if (lane < m) e = edges_s[start + base + lane];
        for (int j = 0; j < m; ++j) {
            int   d = __shfl(e.x, j);
            float v = __int_as_float(__shfl(e.y, j));
            const float* row = (d < USER_NUM)
                             ? (userp + (size_t)d * EMB)
                             : (itemp + (size_t)(d - USER_NUM) * EMB);
            a += v * row[lane];
        }
    }

    size_t o = (size_t)wid * EMB + lane;
    y[o] = a;
    float t = a * (1.0f / (float)N_LAYERS);
    if (layer == 0) acc[o] = t;        // first layer: pure write (out poisoned)
    else            acc[o] += t;
}

// ---------------------------------------------------------------------------

extern "C" void kernel_launch(void* const* d_in, const int* in_sizes, int n_in,
                              void* d_out, int out_size, void* d_ws, size_t ws_size,
                              hipStream_t stream)
{
    const float* user_emb = (const float*)d_in[0];
    const float* item_emb = (const float*)d_in[1];
    const float* edge_val = (const float*)d_in[2];
    const int*   edge_src = (const int*)  d_in[3];
    const int*   edge_dst = (const int*)  d_in[4];
    float* out = (float*)d_out;

    const size_t node_bytes = (size_t)N_NODES * EMB * sizeof(float);  // 76.8 MB

    char* ws = (char*)d_ws;
    float* buf0     = (float*)ws;                 ws += node_bytes;
    float* buf1     = (float*)ws;                 ws += node_bytes;
    int2*  edges_s  = (int2*)ws;                  ws += (size_t)N_EDGES * 8;
    int*   rowptr   = (int*)ws;                   ws += (size_t)N_NODES * 4;
    int*   cnt      = (int*)ws;                   ws += (size_t)N_NODES * 4;
    int*   cursor   = (int*)ws;                   ws += (size_t)N_NODES * 4;
    int*   blockSum = (int*)ws;                   ws += SCAN_NB * 4;

    // ---- CSR build ----
    hipMemsetAsync(cnt, 0, (size_t)N_NODES * 4, stream);
    const int eb = (N_EDGES + 255) / 256;
    hist_kernel   <<<eb, 256, 0, stream>>>(edge_src, cnt);
    scan1_kernel  <<<SCAN_NB, 256, 0, stream>>>(cnt, rowptr, blockSum);
    scan2_kernel  <<<1, 256, 0, stream>>>(blockSum, SCAN_NB);
    scan3_kernel  <<<(N_NODES + 255) / 256, 256, 0, stream>>>(rowptr, cursor, blockSum);
    scatter_kernel<<<eb, 256, 0, stream>>>(edge_src, edge_dst, edge_val, cursor, edges_s);

    // ---- 3 SpMM layers, axpy fused ----
    const int spmm_blocks = (N_NODES * 64 + 255) / 256;   // 1 wave/row, 4 rows/block
    // layer 1: read raw inputs
    spmm_csr<<<spmm_blocks, 256, 0, stream>>>(edges_s, rowptr, cnt,
                                              user_emb, item_emb,
                                              buf0, out, 0);
    // layer 2: buf0 -> buf1
    spmm_csr<<<spmm_blocks, 256, 0, stream>>>(edges_s, rowptr, cnt,
                                              buf0, buf0 + (size_t)USER_NUM * EMB,
                                              buf1, out, 1);
    // layer 3: buf1 -> buf0
    spmm_csr<<<spmm_blocks, 256, 0, stream>>>(edges_s, rowptr, cnt,
                                              buf1, buf1 + (size_t)USER_NUM * EMB,
                                              buf0, out, 2);
}

// Round 3
// 1147.367 us; speedup vs baseline: 10.7960x; 1.4091x over previous
//
#include <hip/hip_runtime.h>

#define USER_NUM 200000
#define ITEM_NUM 100000
#define N_NODES  300000   // USER_NUM + ITEM_NUM
#define EMB      64
#define N_EDGES  4800000
#define N_LAYERS 3

#define SCAN_CHUNK 2048   // elements per scan1 block (256 thr x 8)
#define SCAN_NB    ((N_NODES + SCAN_CHUNK - 1) / SCAN_CHUNK)  // 147

// ---------------- CSR build (runs every call; ~4 passes over edges) --------

__global__ __launch_bounds__(256) void hist_kernel(
    const int* __restrict__ esrc, int* __restrict__ cnt)
{
    int e = blockIdx.x * blockDim.x + threadIdx.x;
    if (e >= N_EDGES) return;
    atomicAdd(&cnt[esrc[e]], 1);
}

// Exclusive scan, stage 1: per-block scan of SCAN_CHUNK elements.
__global__ __launch_bounds__(256) void scan1_kernel(
    const int* __restrict__ cnt, int* __restrict__ rowptr,
    int* __restrict__ blockSums)
{
    __shared__ int lds[256];
    int base = blockIdx.x * SCAN_CHUNK + threadIdx.x * 8;
    int v[8];
    int s = 0;
    #pragma unroll
    for (int i = 0; i < 8; ++i) {
        int idx = base + i;
        v[i] = (idx < N_NODES) ? cnt[idx] : 0;
        s += v[i];
    }
    lds[threadIdx.x] = s;
    __syncthreads();
    for (int off = 1; off < 256; off <<= 1) {
        int t = (threadIdx.x >= off) ? lds[threadIdx.x - off] : 0;
        __syncthreads();
        lds[threadIdx.x] += t;
        __syncthreads();
    }
    int excl = (threadIdx.x == 0) ? 0 : lds[threadIdx.x - 1];
    if (threadIdx.x == 255) blockSums[blockIdx.x] = lds[255];
    int run = excl;
    #pragma unroll
    for (int i = 0; i < 8; ++i) {
        int idx = base + i;
        if (idx < N_NODES) rowptr[idx] = run;
        run += v[i];
    }
}

// Stage 2: exclusive-scan the (147) block sums in-place, single block.
__global__ __launch_bounds__(256) void scan2_kernel(int* __restrict__ blockSums, int nb)
{
    __shared__ int lds[256];
    int v = (threadIdx.x < nb) ? blockSums[threadIdx.x] : 0;
    lds[threadIdx.x] = v;
    __syncthreads();
    for (int off = 1; off < 256; off <<= 1) {
        int t = (threadIdx.x >= off) ? lds[threadIdx.x - off] : 0;
        __syncthreads();
        lds[threadIdx.x] += t;
        __syncthreads();
    }
    int excl = (threadIdx.x == 0) ? 0 : lds[threadIdx.x - 1];
    if (threadIdx.x < nb) blockSums[threadIdx.x] = excl;
}

// Stage 3: add block offsets; init scatter cursors; write rowptr[N] = E.
__global__ __launch_bounds__(256) void scan3_kernel(
    int* __restrict__ rowptr, int* __restrict__ cursor,
    const int* __restrict__ blockSums)
{
    int idx = blockIdx.x * blockDim.x + threadIdx.x;
    if (idx > N_NODES) return;
    if (idx == N_NODES) { rowptr[N_NODES] = N_EDGES; return; }
    int r = rowptr[idx] + blockSums[idx / SCAN_CHUNK];
    rowptr[idx] = r;
    cursor[idx] = r;
}

// Permute edges into CSR order: edges_s[p] = (dst, val) packed 8B.
__global__ __launch_bounds__(256) void scatter_kernel(
    const int* __restrict__ esrc, const int* __restrict__ edst,
    const float* __restrict__ eval, int* __restrict__ cursor,
    int2* __restrict__ edges_s)
{
    int e = blockIdx.x * blockDim.x + threadIdx.x;
    if (e >= N_EDGES) return;
    int s = esrc[e];
    int p = atomicAdd(&cursor[s], 1);
    edges_s[p] = make_int2(edst[e], __float_as_int(eval[e]));
}

// ---------------- CSR SpMM: one wave per row, lane = column -----------------
// y[row][lane] = sum_e val_e * x[dst_e][lane];  acc += y/3 fused.
// Edge (dst,val) are broadcast via readlane -> SGPRs; 8 gather loads issued
// per group before any FMA for memory-level parallelism.
__global__ __launch_bounds__(256) void spmm_csr(
    const int2*  __restrict__ edges_s,
    const int*   __restrict__ rowptr,
    const float* __restrict__ userp,
    const float* __restrict__ itemp,
    float*       __restrict__ y,
    float*       __restrict__ acc,
    int layer)
{
    int wid  = __builtin_amdgcn_readfirstlane(
                   (int)((blockIdx.x * blockDim.x + threadIdx.x) >> 6));
    int lane = threadIdx.x & 63;
    if (wid >= N_NODES) return;

    int start = rowptr[wid];
    int end   = rowptr[wid + 1];

    float a0 = 0.0f, a1 = 0.0f;
    for (int base = start; base < end; base += 64) {
        int m = end - base;
        if (m > 64) m = 64;
        // each lane owns one edge of this chunk; padded lanes contribute v=0
        int2 e = (lane < m) ? edges_s[base + lane] : make_int2(0, 0);
        int groups = (m + 7) >> 3;
        for (int g = 0; g < groups; ++g) {
            int j = g << 3;
            float p[8], vv[8];
            #pragma unroll
            for (int k = 0; k < 8; ++k) {
                int d  = __builtin_amdgcn_readlane(e.x, j + k);   // scalar
                vv[k]  = __int_as_float(__builtin_amdgcn_readlane(e.y, j + k));
                const float* row = (d < USER_NUM)
                                 ? (userp + (size_t)d * EMB)
                                 : (itemp + (size_t)(d - USER_NUM) * EMB);
                p[k] = row[lane];   // 8 independent coalesced 256B wave reads
            }
            a0 += vv[0] * p[0]; a1 += vv[1] * p[1];
            a0 += vv[2] * p[2]; a1 += vv[3] * p[3];
            a0 += vv[4] * p[4]; a1 += vv[5] * p[5];
            a0 += vv[6] * p[6]; a1 += vv[7] * p[7];
        }
    }

    float a = a0 + a1;
    size_t o = (size_t)wid * EMB + lane;
    y[o] = a;
    float t = a * (1.0f / (float)N_LAYERS);
    if (layer == 0) acc[o] = t;        // first layer: pure write (out poisoned)
    else            acc[o] += t;
}

// ---------------------------------------------------------------------------

extern "C" void kernel_launch(void* const* d_in, const int* in_sizes, int n_in,
                              void* d_out, int out_size, void* d_ws, size_t ws_size,
                              hipStream_t stream)
{
    const float* user_emb = (const float*)d_in[0];
    const float* item_emb = (const float*)d_in[1];
    const float* edge_val = (const float*)d_in[2];
    const int*   edge_src = (const int*)  d_in[3];
    const int*   edge_dst = (const int*)  d_in[4];
    float* out = (float*)d_out;

    const size_t node_bytes = (size_t)N_NODES * EMB * sizeof(float);  // 76.8 MB

    char* ws = (char*)d_ws;
    float* buf0     = (float*)ws;                 ws += node_bytes;
    float* buf1     = (float*)ws;                 ws += node_bytes;
    int2*  edges_s  = (int2*)ws;                  ws += (size_t)N_EDGES * 8;
    int*   rowptr   = (int*)ws;                   ws += (size_t)(N_NODES + 1) * 4;
    int*   cnt      = (int*)ws;                   ws += (size_t)N_NODES * 4;
    int*   cursor   = (int*)ws;                   ws += (size_t)N_NODES * 4;
    int*   blockSum = (int*)ws;                   ws += SCAN_NB * 4;

    // ---- CSR build ----
    hipMemsetAsync(cnt, 0, (size_t)N_NODES * 4, stream);
    const int eb = (N_EDGES + 255) / 256;
    hist_kernel   <<<eb, 256, 0, stream>>>(edge_src, cnt);
    scan1_kernel  <<<SCAN_NB, 256, 0, stream>>>(cnt, rowptr, blockSum);
    scan2_kernel  <<<1, 256, 0, stream>>>(blockSum, SCAN_NB);
    scan3_kernel  <<<(N_NODES + 1 + 255) / 256, 256, 0, stream>>>(rowptr, cursor, blockSum);
    scatter_kernel<<<eb, 256, 0, stream>>>(edge_src, edge_dst, edge_val, cursor, edges_s);

    // ---- 3 SpMM layers, axpy fused ----
    const int spmm_blocks = (N_NODES * 64 + 255) / 256;   // 1 wave/row
    spmm_csr<<<spmm_blocks, 256, 0, stream>>>(edges_s, rowptr,
                                              user_emb, item_emb,
                                              buf0, out, 0);
    spmm_csr<<<spmm_blocks, 256, 0, stream>>>(edges_s, rowptr,
                                              buf0, buf0 + (size_t)USER_NUM * EMB,
                                              buf1, out, 1);
    spmm_csr<<<spmm_blocks, 256, 0, stream>>>(edges_s, rowptr,
                                              buf1, buf1 + (size_t)USER_NUM * EMB,
                                              buf0, out, 2);
}

// Round 4
// 1108.078 us; speedup vs baseline: 11.1787x; 1.0355x over previous
//
#include <hip/hip_runtime.h>

#define USER_NUM 200000
#define ITEM_NUM 100000
#define N_NODES  300000   // USER_NUM + ITEM_NUM
#define EMB      64
#define N_EDGES  4800000
#define N_LAYERS 3

#define SCAN_CHUNK 2048   // elements per scan1 block (256 thr x 8)
#define SCAN_NB    ((N_NODES + SCAN_CHUNK - 1) / SCAN_CHUNK)  // 147

#define N_STRIPES     8
#define STRIPE_NODES  (N_NODES / N_STRIPES)   // 37500

// ---------------- CSR build (runs every call) ------------------------------

__global__ __launch_bounds__(256) void hist_kernel(
    const int* __restrict__ esrc, int* __restrict__ cnt)
{
    int e = blockIdx.x * blockDim.x + threadIdx.x;
    if (e >= N_EDGES) return;
    atomicAdd(&cnt[esrc[e]], 1);
}

// Exclusive scan, stage 1: per-block scan of SCAN_CHUNK elements.
__global__ __launch_bounds__(256) void scan1_kernel(
    const int* __restrict__ cnt, int* __restrict__ rowptr,
    int* __restrict__ blockSums)
{
    __shared__ int lds[256];
    int base = blockIdx.x * SCAN_CHUNK + threadIdx.x * 8;
    int v[8];
    int s = 0;
    #pragma unroll
    for (int i = 0; i < 8; ++i) {
        int idx = base + i;
        v[i] = (idx < N_NODES) ? cnt[idx] : 0;
        s += v[i];
    }
    lds[threadIdx.x] = s;
    __syncthreads();
    for (int off = 1; off < 256; off <<= 1) {
        int t = (threadIdx.x >= off) ? lds[threadIdx.x - off] : 0;
        __syncthreads();
        lds[threadIdx.x] += t;
        __syncthreads();
    }
    int excl = (threadIdx.x == 0) ? 0 : lds[threadIdx.x - 1];
    if (threadIdx.x == 255) blockSums[blockIdx.x] = lds[255];
    int run = excl;
    #pragma unroll
    for (int i = 0; i < 8; ++i) {
        int idx = base + i;
        if (idx < N_NODES) rowptr[idx] = run;
        run += v[i];
    }
}

// Stage 2: exclusive-scan the (147) block sums in-place, single block.
__global__ __launch_bounds__(256) void scan2_kernel(int* __restrict__ blockSums, int nb)
{
    __shared__ int lds[256];
    int v = (threadIdx.x < nb) ? blockSums[threadIdx.x] : 0;
    lds[threadIdx.x] = v;
    __syncthreads();
    for (int off = 1; off < 256; off <<= 1) {
        int t = (threadIdx.x >= off) ? lds[threadIdx.x - off] : 0;
        __syncthreads();
        lds[threadIdx.x] += t;
        __syncthreads();
    }
    int excl = (threadIdx.x == 0) ? 0 : lds[threadIdx.x - 1];
    if (threadIdx.x < nb) blockSums[threadIdx.x] = excl;
}

// Stage 3: add block offsets; init scatter cursors; write rowptr[N] = E.
__global__ __launch_bounds__(256) void scan3_kernel(
    int* __restrict__ rowptr, int* __restrict__ cursor,
    const int* __restrict__ blockSums)
{
    int idx = blockIdx.x * blockDim.x + threadIdx.x;
    if (idx > N_NODES) return;
    if (idx == N_NODES) { rowptr[N_NODES] = N_EDGES; return; }
    int r = rowptr[idx] + blockSums[idx / SCAN_CHUNK];
    rowptr[idx] = r;
    cursor[idx] = r;
}

// Striped permute: stripe k (blockIdx.y) handles only src in
// [k*STRIPE_NODES, (k+1)*STRIPE_NODES): the CSR target window is ~4.8 MB so
// scattered 8B writes accumulate full lines in L2 before eviction.
// Blocks dispatch x-fastest, so stripes execute roughly one at a time.
__global__ __launch_bounds__(256) void scatter_kernel(
    const int* __restrict__ esrc, const int* __restrict__ edst,
    const float* __restrict__ eval, int* __restrict__ cursor,
    int2* __restrict__ edges_s)
{
    int e = blockIdx.x * blockDim.x + threadIdx.x;
    if (e >= N_EDGES) return;
    int s = esrc[e];
    int lo = blockIdx.y * STRIPE_NODES;
    if (s < lo || s >= lo + STRIPE_NODES) return;
    int p = atomicAdd(&cursor[s], 1);
    edges_s[p] = make_int2(edst[e], __float_as_int(eval[e]));
}

// ---------------- CSR SpMM: one wave per row, lane = column -----------------
// y[row][lane] = sum_e val_e * x[dst_e][lane];  acc += y/3 fused.
// Edge (dst,val) broadcast via readlane -> SGPRs; 16 gather loads in flight
// per group (deg ~Poisson(16), so one group usually covers the row).
__global__ __launch_bounds__(256) void spmm_csr(
    const int2*  __restrict__ edges_s,
    const int*   __restrict__ rowptr,
    const float* __restrict__ userp,
    const float* __restrict__ itemp,
    float*       __restrict__ y,
    float*       __restrict__ acc,
    int layer)
{
    int wid  = __builtin_amdgcn_readfirstlane(
                   (int)((blockIdx.x * blockDim.x + threadIdx.x) >> 6));
    int lane = threadIdx.x & 63;
    if (wid >= N_NODES) return;

    int start = rowptr[wid];
    int end   = rowptr[wid + 1];

    float a0 = 0.0f, a1 = 0.0f;
    for (int base = start; base < end; base += 64) {
        int m = end - base;
        if (m > 64) m = 64;
        // each lane owns one edge of this chunk; padded lanes contribute v=0
        int2 e = (lane < m) ? edges_s[base + lane] : make_int2(0, 0);
        int groups = (m + 15) >> 4;
        for (int g = 0; g < groups; ++g) {
            int j = g << 4;
            float p[16], vv[16];
            #pragma unroll
            for (int k = 0; k < 16; ++k) {
                int d  = __builtin_amdgcn_readlane(e.x, j + k);   // scalar
                vv[k]  = __int_as_float(__builtin_amdgcn_readlane(e.y, j + k));
                const float* row = (d < USER_NUM)
                                 ? (userp + (size_t)d * EMB)
                                 : (itemp + (size_t)(d - USER_NUM) * EMB);
                p[k] = row[lane];   // 16 independent coalesced 256B wave reads
            }
            #pragma unroll
            for (int k = 0; k < 16; k += 2) {
                a0 += vv[k]     * p[k];
                a1 += vv[k + 1] * p[k + 1];
            }
        }
    }

    float a = a0 + a1;
    size_t o = (size_t)wid * EMB + lane;
    if (layer < N_LAYERS - 1) y[o] = a;   // last layer's y is never read
    float t = a * (1.0f / (float)N_LAYERS);
    if (layer == 0) acc[o] = t;           // first layer: pure write
    else            acc[o] += t;
}

// ---------------------------------------------------------------------------

extern "C" void kernel_launch(void* const* d_in, const int* in_sizes, int n_in,
                              void* d_out, int out_size, void* d_ws, size_t ws_size,
                              hipStream_t stream)
{
    const float* user_emb = (const float*)d_in[0];
    const float* item_emb = (const float*)d_in[1];
    const float* edge_val = (const float*)d_in[2];
    const int*   edge_src = (const int*)  d_in[3];
    const int*   edge_dst = (const int*)  d_in[4];
    float* out = (float*)d_out;

    const size_t node_bytes = (size_t)N_NODES * EMB * sizeof(float);  // 76.8 MB

    char* ws = (char*)d_ws;
    float* buf0     = (float*)ws;                 ws += node_bytes;
    float* buf1     = (float*)ws;                 ws += node_bytes;
    int2*  edges_s  = (int2*)ws;                  ws += (size_t)N_EDGES * 8;
    int*   rowptr   = (int*)ws;                   ws += (size_t)(N_NODES + 1) * 4;
    int*   cnt      = (int*)ws;                   ws += (size_t)N_NODES * 4;
    int*   cursor   = (int*)ws;                   ws += (size_t)N_NODES * 4;
    int*   blockSum = (int*)ws;                   ws += SCAN_NB * 4;

    // ---- CSR build ----
    hipMemsetAsync(cnt, 0, (size_t)N_NODES * 4, stream);
    const int eb = (N_EDGES + 255) / 256;
    hist_kernel <<<eb, 256, 0, stream>>>(edge_src, cnt);
    scan1_kernel<<<SCAN_NB, 256, 0, stream>>>(cnt, rowptr, blockSum);
    scan2_kernel<<<1, 256, 0, stream>>>(blockSum, SCAN_NB);
    scan3_kernel<<<(N_NODES + 1 + 255) / 256, 256, 0, stream>>>(rowptr, cursor, blockSum);
    scatter_kernel<<<dim3(eb, N_STRIPES), 256, 0, stream>>>(
        edge_src, edge_dst, edge_val, cursor, edges_s);

    // ---- 3 SpMM layers, axpy fused ----
    const int spmm_blocks = (N_NODES * 64 + 255) / 256;   // 1 wave/row
    spmm_csr<<<spmm_blocks, 256, 0, stream>>>(edges_s, rowptr,
                                              user_emb, item_emb,
                                              buf0, out, 0);
    spmm_csr<<<spmm_blocks, 256, 0, stream>>>(edges_s, rowptr,
                                              buf0, buf0 + (size_t)USER_NUM * EMB,
                                              buf1, out, 1);
    spmm_csr<<<spmm_blocks, 256, 0, stream>>>(edges_s, rowptr,
                                              buf1, buf1 + (size_t)USER_NUM * EMB,
                                              buf0, out, 2);
}